// Round 2
// baseline (1180.519 us; speedup 1.0000x reference)
//
#include <hip/hip_runtime.h>
#include <hip/hip_bf16.h>

typedef __bf16 bf16_t;
typedef bf16_t bf16x8 __attribute__((ext_vector_type(8)));
typedef float f32x4 __attribute__((ext_vector_type(4)));

#define L_NUM 3
#define E_NUM 4
#define D_DIM 1024
#define B_ROWS 32768
#define BT 32
#define TPB 512
#define N1 272           // 256 V-cols + 4 gating cols + 12 zero pad

#define VT_ELEMS (L_NUM * N1 * D_DIM)            // 835584
#define UT_ELEMS (L_NUM * D_DIM * 256)           // 786432
#define CB_ELEMS (L_NUM * E_NUM * 64 * 64)       // 49152
#define GWS_BYTE_OFF ((VT_ELEMS + UT_ELEMS + CB_ELEMS) * 2)  // 3342336

#define MFMA16(a, b, c) __builtin_amdgcn_mfma_f32_16x16x32_bf16((a), (b), (c), 0, 0, 0)

__device__ __forceinline__ ushort f2b(float f) {
  union { float f; unsigned u; } x; x.f = f;
  unsigned r = (x.u + 0x7fffu + ((x.u >> 16) & 1u)) >> 16;  // RNE
  return (ushort)r;
}
__device__ __forceinline__ float b2f(ushort h) {
  union { unsigned u; float f; } x; x.u = ((unsigned)h) << 16;
  return x.f;
}
__device__ __forceinline__ float u2f_lo(unsigned u) {
  union { unsigned u; float f; } x; x.u = u << 16; return x.f;
}
__device__ __forceinline__ float u2f_hi(unsigned u) {
  union { unsigned u; float f; } x; x.u = u & 0xffff0000u; return x.f;
}
__device__ __forceinline__ float tanh_fast(float x) {
  float cx = fminf(fmaxf(x, -15.f), 15.f);
  float e = __expf(2.f * cx);
  return (e - 1.f) / (e + 1.f);
}
// XOR-swizzled element offset within a [32][COLS] bf16 tile (16B-chunk swizzle).
// Guarantees 2-way-max (free) LDS bank aliasing for MFMA A-fragment reads.
__device__ __forceinline__ int swz(int r, int c, int cols) {
  return r * cols + ((((c >> 3) ^ (r & 7)) << 3) | (c & 7));
}

// ---------------- weight prepack: f32 -> bf16, B^T ([N][K]) layouts ----------------

__global__ void pack_vt_kernel(const float* __restrict__ V, const float* __restrict__ gw,
                               ushort* __restrict__ vt) {
  int idx = blockIdx.x * 256 + threadIdx.x;
  if (idx >= VT_ELEMS) return;
  int d = idx & (D_DIM - 1);
  int n = (idx >> 10) % N1;
  int l = idx / (N1 * D_DIM);
  float val = 0.f;
  if (n < 256) {
    int e = n >> 6, r = n & 63;
    val = V[(((l * E_NUM + e) * D_DIM) + d) * 64 + r];   // Vt[l][e*64+r][d] = V[l,e,d,r]
  } else if (n < 260) {
    val = gw[(n - 256) * D_DIM + d];                     // gating cols
  }
  vt[idx] = f2b(val);
}

__global__ void pack_ut_kernel(const float* __restrict__ U, ushort* __restrict__ ut) {
  int idx = blockIdx.x * 256 + threadIdx.x;
  if (idx >= UT_ELEMS) return;
  int er = idx & 255;
  int d = (idx >> 8) & (D_DIM - 1);
  int l = idx >> 18;
  int e = er >> 6, r = er & 63;
  ut[idx] = f2b(U[((l * E_NUM + e) * D_DIM + d) * 64 + r]);  // Ut[l][d][e*64+r]
}

__global__ void pack_cb_kernel(const float* __restrict__ C, ushort* __restrict__ cb) {
  int idx = blockIdx.x * 256 + threadIdx.x;
  if (idx >= CB_ELEMS) return;
  cb[idx] = f2b(C[idx]);   // C[l,e,r,s] already is Bt[n=r][k=s]
}

// ---------------- fused 3-layer CrossNet: each block owns 32 rows end-to-end ----------------
// LDS exactly 80 KB -> 2 blocks/CU; launch_bounds(512,4) caps VGPR at 128 -> 16 waves/CU.

__global__ __launch_bounds__(TPB, 4) void crossnet_fused(
    const float* __restrict__ inputs, const float* __restrict__ bias,
    const ushort* __restrict__ Vt, const ushort* __restrict__ Ut,
    const ushort* __restrict__ Cb, float* __restrict__ gws,
    float* __restrict__ out) {
  __shared__ ushort xl[BT * 1024];   // 65536 B, swizzled
  __shared__ ushort t1s[BT * 256];   // 16384 B, swizzled

  const int tid = threadIdx.x;
  const int wave = tid >> 6;
  const int lane = tid & 63;
  const int l15 = lane & 15;
  const int quad = lane >> 4;
  const int r7 = l15 & 7;
  const long rowbase = (long)blockIdx.x * BT;
  float* gwb = gws + (long)blockIdx.x * (BT * E_NUM);

  // ---- stage inputs -> xl (bf16, swizzled; coalesced float4 loads) ----
  #pragma unroll
  for (int i = 0; i < 16; ++i) {
    int idx = tid + i * TPB;       // float4 index within [32][256]
    int r = idx >> 8;
    int c4 = idx & 255;
    float4 v = ((const float4*)(inputs + (rowbase + r) * D_DIM))[c4];
    ushort4 h;
    h.x = f2b(v.x); h.y = f2b(v.y); h.z = f2b(v.z); h.w = f2b(v.w);
    int off = r * 1024 + ((((c4 >> 1) ^ (r & 7)) << 3) | ((c4 & 1) << 2));
    *(ushort4*)&xl[off] = h;
  }
  __syncthreads();

  // ---- x0 held as packed bf16 in 32 VGPRs, at this wave's GEMM2 C-layout positions ----
  // c8 in 0..7 -> col = wave*128 + c8*16 + l15 ; rows m*16 + quad*4 + {2pr, 2pr+1}
  unsigned x0p[8][2][2];
  #pragma unroll
  for (int c8 = 0; c8 < 8; ++c8) {
    int col = wave * 128 + c8 * 16 + l15;
    #pragma unroll
    for (int m = 0; m < 2; ++m)
      #pragma unroll
      for (int pr = 0; pr < 2; ++pr) {
        int r0 = m * 16 + quad * 4 + 2 * pr;
        unsigned lo = xl[swz(r0, col, 1024)];
        unsigned hi = xl[swz(r0 + 1, col, 1024)];
        x0p[c8][m][pr] = lo | (hi << 16);
      }
  }

  const f32x4 zf = {0.f, 0.f, 0.f, 0.f};

  for (int l = 0; l < L_NUM; ++l) {
    const ushort* vtl = Vt + l * N1 * D_DIM;
    const ushort* utl = Ut + l * D_DIM * 256;
    const ushort* cbl = Cb + l * E_NUM * 64 * 64;

    // ================= Phase A: T1[32,272] = xl[32,1024] @ [V|gw]^T =================
    f32x4 acc1[3][2];
    #pragma unroll
    for (int t = 0; t < 3; ++t) { acc1[t][0] = zf; acc1[t][1] = zf; }

    const ushort* vb0 = vtl + (wave * 32 + l15) * D_DIM + quad * 8;
    const ushort* vb1 = vb0 + 16 * D_DIM;
    const int abase = l15 * 1024;
    if (wave == 7) {  // wave 7 also computes the gating tile (cols 256..271)
      const ushort* vb2 = vtl + (256 + l15) * D_DIM + quad * 8;
      #pragma unroll 4
      for (int t = 0; t < 32; ++t) {
        int ch = ((4 * t + quad) ^ r7) << 3;
        bf16x8 a0 = *(const bf16x8*)&xl[abase + ch];
        bf16x8 a1 = *(const bf16x8*)&xl[abase + ch + 16 * 1024];
        bf16x8 b0 = *(const bf16x8*)(vb0 + t * 32);
        bf16x8 b1 = *(const bf16x8*)(vb1 + t * 32);
        bf16x8 b2 = *(const bf16x8*)(vb2 + t * 32);
        acc1[0][0] = MFMA16(a0, b0, acc1[0][0]);
        acc1[0][1] = MFMA16(a1, b0, acc1[0][1]);
        acc1[1][0] = MFMA16(a0, b1, acc1[1][0]);
        acc1[1][1] = MFMA16(a1, b1, acc1[1][1]);
        acc1[2][0] = MFMA16(a0, b2, acc1[2][0]);
        acc1[2][1] = MFMA16(a1, b2, acc1[2][1]);
      }
    } else {
      #pragma unroll 4
      for (int t = 0; t < 32; ++t) {
        int ch = ((4 * t + quad) ^ r7) << 3;
        bf16x8 a0 = *(const bf16x8*)&xl[abase + ch];
        bf16x8 a1 = *(const bf16x8*)&xl[abase + ch + 16 * 1024];
        bf16x8 b0 = *(const bf16x8*)(vb0 + t * 32);
        bf16x8 b1 = *(const bf16x8*)(vb1 + t * 32);
        acc1[0][0] = MFMA16(a0, b0, acc1[0][0]);
        acc1[0][1] = MFMA16(a1, b0, acc1[0][1]);
        acc1[1][0] = MFMA16(a0, b1, acc1[1][0]);
        acc1[1][1] = MFMA16(a1, b1, acc1[1][1]);
      }
    }

    // epilogue: v1 = tanh(T1) -> t1s (swizzled); wave 7 does softmax in-wave -> gws
    #pragma unroll
    for (int tt = 0; tt < 2; ++tt) {
      int ncol = wave * 32 + tt * 16 + l15;
      #pragma unroll
      for (int m = 0; m < 2; ++m)
        #pragma unroll
        for (int rg = 0; rg < 4; ++rg) {
          int row = m * 16 + quad * 4 + rg;
          t1s[swz(row, ncol, 256)] = f2b(tanh_fast(acc1[tt][m][rg]));
        }
    }
    if (wave == 7) {
      #pragma unroll
      for (int m = 0; m < 2; ++m)
        #pragma unroll
        for (int rg = 0; rg < 4; ++rg) {
          float g = acc1[2][m][rg];                 // logit for expert l15 (valid l15<4)
          float mx = fmaxf(g, __shfl_xor(g, 1));
          mx = fmaxf(mx, __shfl_xor(mx, 2));
          float ex = __expf(g - mx);
          float s = ex + __shfl_xor(ex, 1);
          s = s + __shfl_xor(s, 2);
          if (l15 < 4) {
            int row = m * 16 + quad * 4 + rg;
            gwb[row * 4 + l15] = ex / s;
          }
        }
    }
    __syncthreads();   // (1) t1s(v1) + gate visible

    // ================= Phase C: block-diag v2 = tanh(C @ v1), w = gate*v2 =================
    const int e = wave >> 1;   // expert
    const int nh = wave & 1;   // 32-col half of this expert's 64 outputs
    f32x4 acc2[2][2];
    acc2[0][0] = zf; acc2[0][1] = zf; acc2[1][0] = zf; acc2[1][1] = zf;
    {
      const ushort* cb0 = cbl + (e * 64 + nh * 32 + l15) * 64 + quad * 8;
      const ushort* cb1 = cb0 + 16 * 64;
      #pragma unroll
      for (int t = 0; t < 2; ++t) {
        int ch = ((8 * e + 4 * t + quad) ^ r7) << 3;
        bf16x8 a0 = *(const bf16x8*)&t1s[l15 * 256 + ch];
        bf16x8 a1 = *(const bf16x8*)&t1s[l15 * 256 + ch + 16 * 256];
        bf16x8 b0 = *(const bf16x8*)(cb0 + t * 32);
        bf16x8 b1 = *(const bf16x8*)(cb1 + t * 32);
        acc2[0][0] = MFMA16(a0, b0, acc2[0][0]);
        acc2[0][1] = MFMA16(a1, b0, acc2[0][1]);
        acc2[1][0] = MFMA16(a0, b1, acc2[1][0]);
        acc2[1][1] = MFMA16(a1, b1, acc2[1][1]);
      }
    }
    // gate values for this thread's 8 rows (hit L1; written by this block pre-barrier)
    float g8[2][4];
    #pragma unroll
    for (int m = 0; m < 2; ++m)
      #pragma unroll
      for (int rg = 0; rg < 4; ++rg)
        g8[m][rg] = gwb[(m * 16 + quad * 4 + rg) * 4 + e];
    __syncthreads();   // (2) all v1 reads done -> safe to overwrite t1s
    #pragma unroll
    for (int tt = 0; tt < 2; ++tt) {
      int ncol = e * 64 + nh * 32 + tt * 16 + l15;
      #pragma unroll
      for (int m = 0; m < 2; ++m)
        #pragma unroll
        for (int rg = 0; rg < 4; ++rg) {
          int row = m * 16 + quad * 4 + rg;
          t1s[swz(row, ncol, 256)] = f2b(g8[m][rg] * tanh_fast(acc2[tt][m][rg]));
        }
    }
    __syncthreads();   // (3) w complete

    // ================= Phase D: S[32,1024] = w[32,256] @ Ut^T (two 64-col halves) ==========
    #pragma unroll
    for (int half = 0; half < 2; ++half) {
      f32x4 acc3[4][2];
      #pragma unroll
      for (int nt = 0; nt < 4; ++nt) { acc3[nt][0] = zf; acc3[nt][1] = zf; }
      const ushort* ub = utl + (wave * 128 + half * 64 + l15) * 256 + quad * 8;
      #pragma unroll
      for (int t = 0; t < 8; ++t) {
        int ch = ((4 * t + quad) ^ r7) << 3;
        bf16x8 a0 = *(const bf16x8*)&t1s[l15 * 256 + ch];
        bf16x8 a1 = *(const bf16x8*)&t1s[l15 * 256 + ch + 16 * 256];
        #pragma unroll
        for (int nt = 0; nt < 4; ++nt) {
          bf16x8 b = *(const bf16x8*)(ub + nt * 16 * 256 + t * 32);
          acc3[nt][0] = MFMA16(a0, b, acc3[nt][0]);
          acc3[nt][1] = MFMA16(a1, b, acc3[nt][1]);
        }
      }
      // epilogue: x_new = x_l + x0*(S + bias[l])
      #pragma unroll
      for (int nt = 0; nt < 4; ++nt) {
        int c8 = half * 4 + nt;
        int col = wave * 128 + c8 * 16 + l15;
        float bv = bias[l * D_DIM + col];
        #pragma unroll
        for (int m = 0; m < 2; ++m)
          #pragma unroll
          for (int pr = 0; pr < 2; ++pr) {
            unsigned u = x0p[c8][m][pr];
            float x0e = u2f_lo(u), x0o = u2f_hi(u);
            int r0 = m * 16 + quad * 4 + 2 * pr;
            float xe = b2f(xl[swz(r0, col, 1024)]) + x0e * (acc3[nt][m][2 * pr] + bv);
            float xo = b2f(xl[swz(r0 + 1, col, 1024)]) + x0o * (acc3[nt][m][2 * pr + 1] + bv);
            if (l < 2) {
              xl[swz(r0, col, 1024)] = f2b(xe);
              xl[swz(r0 + 1, col, 1024)] = f2b(xo);
            } else {
              out[(rowbase + r0) * D_DIM + col] = xe;
              out[(rowbase + r0 + 1) * D_DIM + col] = xo;
            }
          }
      }
    }
    __syncthreads();   // (4) xl updated; t1s free for next layer
  }
}

extern "C" void kernel_launch(void* const* d_in, const int* in_sizes, int n_in,
                              void* d_out, int out_size, void* d_ws, size_t ws_size,
                              hipStream_t stream) {
  (void)in_sizes; (void)n_in; (void)out_size; (void)ws_size;
  const float* inputs = (const float*)d_in[0];
  const float* U      = (const float*)d_in[1];
  const float* V      = (const float*)d_in[2];
  const float* C      = (const float*)d_in[3];
  const float* gw     = (const float*)d_in[4];
  const float* bias   = (const float*)d_in[5];
  float* out = (float*)d_out;

  ushort* vt = (ushort*)d_ws;          // 3*272*1024 bf16
  ushort* ut = vt + VT_ELEMS;          // 3*1024*256 bf16
  ushort* cb = ut + UT_ELEMS;          // 3*4*64*64  bf16
  float* gws = (float*)((char*)d_ws + GWS_BYTE_OFF);  // 1024 blocks * 128 floats

  pack_vt_kernel<<<(VT_ELEMS + 255) / 256, 256, 0, stream>>>(V, gw, vt);
  pack_ut_kernel<<<(UT_ELEMS + 255) / 256, 256, 0, stream>>>(U, ut);
  pack_cb_kernel<<<(CB_ELEMS + 255) / 256, 256, 0, stream>>>(C, cb);

  crossnet_fused<<<B_ROWS / BT, TPB, 0, stream>>>(inputs, bias, vt, ut, cb, gws, out);
}